// Round 2
// baseline (284.611 us; speedup 1.0000x reference)
//
#include <hip/hip_runtime.h>
#include <math.h>

#define D 2048
#define EPS_COS 1e-8f
#define EPS_DEN 1e-6f
#define INV_TEMP 10.0f
#define TPB 256
#define NBLOCKS 2048
#define WPB (TPB / 64)
#define NWAVES (NBLOCKS * WPB)   // 8192 waves -> 2 rows/wave at N=16384

// pos_pair: reference declares int64 but JAX x64-off makes it int32.
// Hedge: accept int32 reading iff plausible (in range, i != j), else int64.
__device__ __forceinline__ void get_ij(const int* __restrict__ p, int n,
                                       int& i, int& j) {
    int i32 = p[0], j32 = p[1];
    if (i32 >= 0 && i32 < n && j32 >= 0 && j32 < n && i32 != j32) {
        i = i32; j = j32; return;
    }
    const long long* p64 = (const long long*)p;
    i = (int)p64[0]; j = (int)p64[1];
}

// Wave-per-row: each 64-lane wave holds its slice of xi in registers (8 float4
// = 32 VGPR), streams rows with 8 outstanding float4 loads/lane, wave-shuffle
// reduces. Loss fused via atomics + last-block-done counter.
// acc[0]=denominator, acc[1]=e[j], acc[2]=done counter (all zeroed by memset).
__global__ __launch_bounds__(TPB)
void fused_kernel(const float* __restrict__ x, const int* __restrict__ pos,
                  float* __restrict__ out, float* __restrict__ acc, int n) {
    int i, j;
    get_ij(pos, n, i, j);
    const int lane  = threadIdx.x & 63;
    const int wave  = threadIdx.x >> 6;
    const int gwave = blockIdx.x * WPB + wave;

    // xi slice, loaded once (L1-resident after first block per CU)
    const float4* __restrict__ xi = (const float4*)(x + (size_t)i * D);
    float4 b[8];
#pragma unroll
    for (int w = 0; w < 8; ++w) b[w] = xi[lane + w * 64];

    float sqi = 0.f;
#pragma unroll
    for (int w = 0; w < 8; ++w)
        sqi = fmaf(b[w].x, b[w].x, fmaf(b[w].y, b[w].y,
              fmaf(b[w].z, b[w].z, fmaf(b[w].w, b[w].w, sqi))));
#pragma unroll
    for (int off = 32; off; off >>= 1) sqi += __shfl_down(sqi, off);
    const float ni = fmaxf(sqrtf(sqi), EPS_COS);   // valid in lane 0 only

    float local_den = 0.f;
    float local_ej  = 0.f;

    for (int row = gwave; row < n; row += NWAVES) {
        const float4* __restrict__ xk = (const float4*)(x + (size_t)row * D);
        float4 a[8];
#pragma unroll
        for (int w = 0; w < 8; ++w) a[w] = xk[lane + w * 64];
        float dot = 0.f, sq = 0.f;
#pragma unroll
        for (int w = 0; w < 8; ++w) {
            dot = fmaf(a[w].x, b[w].x, fmaf(a[w].y, b[w].y,
                  fmaf(a[w].z, b[w].z, fmaf(a[w].w, b[w].w, dot))));
            sq  = fmaf(a[w].x, a[w].x, fmaf(a[w].y, a[w].y,
                  fmaf(a[w].z, a[w].z, fmaf(a[w].w, a[w].w, sq))));
        }
#pragma unroll
        for (int off = 32; off; off >>= 1) {
            dot += __shfl_down(dot, off);
            sq  += __shfl_down(sq,  off);
        }
        if (lane == 0) {
            float nk = fmaxf(sqrtf(sq), EPS_COS);
            float e  = expf(INV_TEMP * dot / (nk * ni));
            if (row != i) local_den += e;
            if (row == j) local_ej = e;
        }
    }

    __shared__ float s_den[WPB];
    if (lane == 0) {
        s_den[wave] = local_den;
        if (local_ej != 0.f) atomicAdd(&acc[1], local_ej);  // only the j-wave
    }
    __syncthreads();
    if (threadIdx.x == 0) {
        float bden = 0.f;
#pragma unroll
        for (int w = 0; w < WPB; ++w) bden += s_den[w];
        atomicAdd(&acc[0], bden);
        __threadfence();
        unsigned old = atomicAdd((unsigned*)&acc[2], 1u);
        if (old == gridDim.x - 1) {             // last block: finish the loss
            float den = atomicAdd(&acc[0], 0.f);  // coherent atomic read
            float ej  = atomicAdd(&acc[1], 0.f);
            out[0] = -logf(ej / (den + EPS_DEN));
        }
    }
}

extern "C" void kernel_launch(void* const* d_in, const int* in_sizes, int n_in,
                              void* d_out, int out_size, void* d_ws, size_t ws_size,
                              hipStream_t stream) {
    const float* x   = (const float*)d_in[0];
    const int*   pos = (const int*)d_in[1];
    float*       out = (float*)d_out;
    float*       acc = (float*)d_ws;

    const int n = in_sizes[0] / D;          // 16384

    hipMemsetAsync(d_ws, 0, 16, stream);    // zero acc[0..3] (graph-capturable)
    fused_kernel<<<NBLOCKS, TPB, 0, stream>>>(x, pos, out, acc, n);
}

// Round 3
// 191.079 us; speedup vs baseline: 1.4895x; 1.4895x over previous
//
#include <hip/hip_runtime.h>
#include <math.h>

#define D 2048
#define EPS_COS 1e-8f
#define EPS_DEN 1e-6f
#define INV_TEMP 10.0f
#define TPB 256
#define WPB (TPB / 64)
#define NBLOCKS 2048           // 8192 waves; 2 contiguous rows per wave = 16384 rows

// pos_pair: reference declares int64 but JAX x64-off makes it int32.
// Hedge: accept int32 reading iff plausible (in range, i != j), else int64.
__device__ __forceinline__ void get_ij(const int* __restrict__ p, int n,
                                       int& i, int& j) {
    int i32 = p[0], j32 = p[1];
    if (i32 >= 0 && i32 < n && j32 >= 0 && j32 < n && i32 != j32) {
        i = i32; j = j32; return;
    }
    const long long* p64 = (const long long*)p;
    i = (int)p64[0]; j = (int)p64[1];
}

// Kernel 1: wave-per-2-rows, xi held in registers, all 16 row-loads issued
// before the reduce chains, no LDS / no __syncthreads / no atomics.
__global__ __launch_bounds__(TPB)
void e_kernel(const float* __restrict__ x, const int* __restrict__ pos,
              float* __restrict__ e_out, int n) {
    int i, j;
    get_ij(pos, n, i, j);
    const int lane  = threadIdx.x & 63;
    const int wave  = threadIdx.x >> 6;
    const int gwave = blockIdx.x * WPB + wave;
    const int row0  = gwave * 2;
    if (row0 >= n) return;

    // xi slice in registers (8 float4 = 32 VGPR); L1/L2-resident broadcast
    const float4* __restrict__ xi = (const float4*)(x + (size_t)i * D);
    float4 b[8];
#pragma unroll
    for (int w = 0; w < 8; ++w) b[w] = xi[lane + w * 64];

    float sqi = 0.f;
#pragma unroll
    for (int w = 0; w < 8; ++w)
        sqi = fmaf(b[w].x, b[w].x, fmaf(b[w].y, b[w].y,
              fmaf(b[w].z, b[w].z, fmaf(b[w].w, b[w].w, sqi))));
#pragma unroll
    for (int off = 32; off; off >>= 1) sqi += __shfl_down(sqi, off);
    const float ni = fmaxf(sqrtf(sqi), EPS_COS);   // valid in lane 0

    // issue both rows' loads up front (16 float4 in flight per lane)
    const float4* __restrict__ r0 = (const float4*)(x + (size_t)row0 * D);
    const float4* __restrict__ r1 = (const float4*)(x + (size_t)(row0 + 1) * D);
    float4 a0[8], a1[8];
#pragma unroll
    for (int w = 0; w < 8; ++w) a0[w] = r0[lane + w * 64];
#pragma unroll
    for (int w = 0; w < 8; ++w) a1[w] = r1[lane + w * 64];

    float d0 = 0.f, s0 = 0.f, d1 = 0.f, s1 = 0.f;
#pragma unroll
    for (int w = 0; w < 8; ++w) {
        d0 = fmaf(a0[w].x, b[w].x, fmaf(a0[w].y, b[w].y,
             fmaf(a0[w].z, b[w].z, fmaf(a0[w].w, b[w].w, d0))));
        s0 = fmaf(a0[w].x, a0[w].x, fmaf(a0[w].y, a0[w].y,
             fmaf(a0[w].z, a0[w].z, fmaf(a0[w].w, a0[w].w, s0))));
        d1 = fmaf(a1[w].x, b[w].x, fmaf(a1[w].y, b[w].y,
             fmaf(a1[w].z, b[w].z, fmaf(a1[w].w, b[w].w, d1))));
        s1 = fmaf(a1[w].x, a1[w].x, fmaf(a1[w].y, a1[w].y,
             fmaf(a1[w].z, a1[w].z, fmaf(a1[w].w, a1[w].w, s1))));
    }
#pragma unroll
    for (int off = 32; off; off >>= 1) {
        d0 += __shfl_down(d0, off);
        s0 += __shfl_down(s0, off);
        d1 += __shfl_down(d1, off);
        s1 += __shfl_down(s1, off);
    }
    if (lane == 0) {
        float e0 = expf(INV_TEMP * d0 / (fmaxf(sqrtf(s0), EPS_COS) * ni));
        float e1 = expf(INV_TEMP * d1 / (fmaxf(sqrtf(s1), EPS_COS) * ni));
        e_out[row0]     = e0;
        e_out[row0 + 1] = e1;
    }
}

// Kernel 2: single block; sum e (float4 loads), exclude e[i], finish loss.
__global__ __launch_bounds__(1024)
void loss_kernel(const float* __restrict__ e, const int* __restrict__ pos,
                 float* __restrict__ out, int n) {
    int i, j;
    get_ij(pos, n, i, j);
    const int t = threadIdx.x;
    const float4* __restrict__ e4 = (const float4*)e;

    float s = 0.f;
    for (int k = t; k < n / 4; k += 1024) {
        float4 v = e4[k];
        s += (v.x + v.y) + (v.z + v.w);
    }
#pragma unroll
    for (int off = 32; off; off >>= 1) s += __shfl_down(s, off);

    __shared__ float ls[16];
    if ((t & 63) == 0) ls[t >> 6] = s;
    __syncthreads();

    if (t == 0) {
        float tot = 0.f;
#pragma unroll
        for (int w = 0; w < 16; ++w) tot += ls[w];
        float den = tot - e[i];
        out[0] = -logf(e[j] / (den + EPS_DEN));
    }
}

extern "C" void kernel_launch(void* const* d_in, const int* in_sizes, int n_in,
                              void* d_out, int out_size, void* d_ws, size_t ws_size,
                              hipStream_t stream) {
    const float* x   = (const float*)d_in[0];
    const int*   pos = (const int*)d_in[1];
    float*       out = (float*)d_out;
    float*       e   = (float*)d_ws;        // n floats of scratch

    const int n = in_sizes[0] / D;          // 16384

    e_kernel<<<NBLOCKS, TPB, 0, stream>>>(x, pos, e, n);
    loss_kernel<<<1, 1024, 0, stream>>>(e, pos, out, n);
}